// Round 10
// baseline (45.182 us; speedup 1.0000x reference)
//
#include <hip/hip_runtime.h>

#define OUT_F 11008
#define IN_F  4096
#define KQ    (IN_F / 4)       // 1024: K-quarter per wave
#define KSTEP 256              // k per step: lane*4, 16B loads
#define NSTEP (KQ / KSTEP)     // 4 steps per wave

// R9: maximize TLP. Block = 256 threads = 4 waves = the 4 K-quarters of ONE
// 4-row group. Wave = 4 rows x 8 batches x 1024 K. Grid = 2752 blocks =
// 11008 waves = 43 waves/CU supply. Register budget kept < 128 (acc 32 +
// asum 8 + x 32 single-buffered + w-dbuf 32 + addr) -> 4 waves/SIMD
// resident, ~6x R8's measured average residency. x is single-buffered:
// its ~200-400cy L2 latency is covered by 4-way TLP per SIMD rather than
// by per-wave prefetch (saves 32 VGPR). w keeps depth-1 register double
// buffering (16B int4 loads; R5 proved 8B loads cost 18%).
// zero-point folded: out = s*(dot - zp*rowsum(x)) + bias; each wave sums
// its K-quarter of x; LDS epilogue (640 B) combines the 4 quarters.
// NOTE: plain __launch_bounds__ — ",N" variants forced spills (R3).
__global__ __launch_bounds__(256) void qlinear_kernel(
        const float* __restrict__ in, const int* __restrict__ qw,
        const int* __restrict__ zp, const float* __restrict__ scale,
        const float* __restrict__ bias, float* __restrict__ out) {
    const int lane = threadIdx.x & 63;
    const int q    = threadIdx.x >> 6;       // K-quarter 0..3
    const int row0 = blockIdx.x * 4;
    const int l4   = lane * 4;

    const int*   qp = qw + (size_t)row0 * IN_F + q * KQ + l4;
    const float* xp = in + q * KQ + l4;

    float acc[4][8];
    float asum[8];
    #pragma unroll
    for (int r = 0; r < 4; ++r)
        #pragma unroll
        for (int b = 0; b < 8; ++b) acc[r][b] = 0.f;
    #pragma unroll
    for (int b = 0; b < 8; ++b) asum[b] = 0.f;

    int4 wbuf[2][4];
    #pragma unroll
    for (int r = 0; r < 4; ++r)
        wbuf[0][r] = *reinterpret_cast<const int4*>(qp + r * IN_F);

    #pragma unroll
    for (int t = 0; t < NSTEP; ++t) {        // 4 steps, fully unrolled
        const int c = t & 1, n = c ^ 1;

        // x(t): single-buffered, issued before w(t+1) so the FMA's x-wait
        // (vmcnt(4)) retires w(t) but keeps w(t+1) in flight.
        float4 x[8];
        #pragma unroll
        for (int b = 0; b < 8; ++b)
            x[b] = *reinterpret_cast<const float4*>(xp + b * IN_F + t * KSTEP);

        // w(t+1): depth-1 prefetch
        if (t + 1 < NSTEP) {
            #pragma unroll
            for (int r = 0; r < 4; ++r)
                wbuf[n][r] = *reinterpret_cast<const int4*>(qp + r * IN_F + (t + 1) * KSTEP);
        }

        float f[4][4];
        #pragma unroll
        for (int r = 0; r < 4; ++r) {
            f[r][0] = (float)wbuf[c][r].x;
            f[r][1] = (float)wbuf[c][r].y;
            f[r][2] = (float)wbuf[c][r].z;
            f[r][3] = (float)wbuf[c][r].w;
        }
        #pragma unroll
        for (int b = 0; b < 8; ++b) {
            const float4 xv = x[b];
            asum[b] += (xv.x + xv.y) + (xv.z + xv.w);
            #pragma unroll
            for (int r = 0; r < 4; ++r)
                acc[r][b] += f[r][0] * xv.x + f[r][1] * xv.y
                           + f[r][2] * xv.z + f[r][3] * xv.w;
        }
    }

    // --- cross-lane reduce of 32 accumulators (register-halving tree):
    // 5 levels -> lane l holds index (l&31) over its 32-lane half; +xor32
    // -> full 64-lane sum on lanes 0..31. index = r*8 + b.
    float v[32];
    #pragma unroll
    for (int r = 0; r < 4; ++r)
        #pragma unroll
        for (int b = 0; b < 8; ++b) v[r * 8 + b] = acc[r][b];

    #pragma unroll
    for (int k = 0; k < 5; ++k) {
        const bool hi = (lane >> k) & 1;
        const int  nn = 32 >> k;
        #pragma unroll
        for (int i = 0; i < 32; ++i) {
            if (i < nn / 2) {
                float keep = hi ? v[2 * i + 1] : v[2 * i];
                float send = hi ? v[2 * i]     : v[2 * i + 1];
                v[i] = keep + __shfl_xor(send, 1 << k);
            }
        }
    }
    const float total = v[0] + __shfl_xor(v[0], 32);   // this wave's K-quarter dot

    // --- reduce 8 row-sum accumulators -> this quarter's rowsum of batch (lane&7)
    float s8[8];
    #pragma unroll
    for (int b = 0; b < 8; ++b) s8[b] = asum[b];
    #pragma unroll
    for (int k = 0; k < 3; ++k) {
        const bool hi = (lane >> k) & 1;
        const int  nn = 8 >> k;
        #pragma unroll
        for (int i = 0; i < 8; ++i) {
            if (i < nn / 2) {
                float keep = hi ? s8[2 * i + 1] : s8[2 * i];
                float send = hi ? s8[2 * i]     : s8[2 * i + 1];
                s8[i] = keep + __shfl_xor(send, 1 << k);
            }
        }
    }
    float S = s8[0];
    S += __shfl_xor(S, 8);
    S += __shfl_xor(S, 16);
    S += __shfl_xor(S, 32);   // quarter rowsum of batch (lane&7)

    // --- combine the 4 K-quarters via LDS (640 B) ---
    __shared__ float ldsv[4][32];
    __shared__ float ldsS[4][8];
    if (lane < 32) ldsv[q][lane] = total;
    if (lane < 8)  ldsS[q][lane] = S;
    __syncthreads();

    if (q == 0 && lane < 32) {
        const int r = lane >> 3;          // 0..3
        const int b = lane & 7;           // 0..7
        const int o = row0 + r;
        const float tot = ldsv[0][lane] + ldsv[1][lane] + ldsv[2][lane] + ldsv[3][lane];
        const float Sf  = ldsS[0][b] + ldsS[1][b] + ldsS[2][b] + ldsS[3][b];
        out[(size_t)b * OUT_F + o] =
            scale[o] * (tot - (float)zp[o] * Sf) + bias[o];
    }
}

extern "C" void kernel_launch(void* const* d_in, const int* in_sizes, int n_in,
                              void* d_out, int out_size, void* d_ws, size_t ws_size,
                              hipStream_t stream) {
    const float* in    = (const float*)d_in[0];
    const int*   qw    = (const int*)  d_in[1];
    const int*   zp    = (const int*)  d_in[2];
    const float* scale = (const float*)d_in[3];
    const float* bias  = (const float*)d_in[4];
    float*       out   = (float*)d_out;

    const int blocks = OUT_F / 4;   // 2752 blocks x 4 waves (K-quarters)
    qlinear_kernel<<<blocks, 256, 0, stream>>>(in, qw, zp, scale, bias, out);
}